// Round 3
// baseline (365.974 us; speedup 1.0000x reference)
//
#include <hip/hip_runtime.h>

typedef short s16x8 __attribute__((ext_vector_type(8)));
typedef float f32x4 __attribute__((ext_vector_type(4)));
typedef unsigned short u16;

namespace {

constexpr int NHEAD = 4;
constexpr int CDIM  = 128;
constexpr int NTOK  = 49;
constexpr int IMG   = 56;
constexpr int NBLK  = 4096;
constexpr float QSCALE = 0.17677669529663687f;  // 32^-0.5

__device__ inline u16 f2bf(float x) {
  unsigned u = __float_as_uint(x);
  u += 0x7fffu + ((u >> 16) & 1u);
  return (u16)(u >> 16);
}
__device__ inline float bf2f(u16 h) { return __uint_as_float(((unsigned)h) << 16); }
__device__ inline int div7(int t) { return (t * 9363) >> 16; }  // valid t<64

// ---- prep: bf16 weights + combined bias/mask/pad table (all L2-resident) ----
// btab[cls][h][n][m]: rel-pos bias + shift-mask(-100) + col-pad(-1e9), bf16.
// Only 4 window classes: (wy==7?)x(wx==7?).
__global__ void prep(const float* __restrict__ qkvw, const float* __restrict__ projw,
                     const float* __restrict__ rpb,
                     u16* __restrict__ wq, u16* __restrict__ wp, u16* __restrict__ btab) {
  int i = blockIdx.x * 256 + threadIdx.x;
  if (i < 384 * 128) wq[i] = f2bf(qkvw[i]);
  if (i < 128 * 128) wp[i] = f2bf(projw[i]);
  if (i < 65536) {
    int m = i & 63, n = (i >> 6) & 63, h = (i >> 12) & 3, cls = (i >> 14) & 3;
    float v;
    if (m >= NTOK) v = -1e9f;
    else if (n >= NTOK) v = 0.f;
    else {
      int tin = div7(n), tjn = n - tin * 7;
      int tim = div7(m), tjm = m - tim * 7;
      int ridx = 13 * (tin - tim + 6) + (tjn - tjm + 6);
      v = rpb[ridx * NHEAD + h];
      int wy = (cls & 2) ? 7 : 0, wx = (cls & 1) ? 7 : 0;
      int mhn = wy * 7 + tin, mwn = wx * 7 + tjn;
      int mhm = wy * 7 + tim, mwm = wx * 7 + tjm;
      int cn = ((mhn < 49) ? 0 : ((mhn < 53) ? 1 : 2)) * 3 + ((mwn < 49) ? 0 : ((mwn < 53) ? 1 : 2));
      int cm = ((mhm < 49) ? 0 : ((mhm < 53) ? 1 : 2)) * 3 + ((mwm < 49) ? 0 : ((mwm < 53) ? 1 : 2));
      if (cn != cm) v -= 100.f;
    }
    btab[i] = f2bf(v);
  }
}

// LDS swizzles (write and read must agree; reads are 16B-aligned ds_read_b128):
// [64][32] bf16 tile
__device__ inline int adr32(int r, int c) {
  return r * 32 + (c & 7) + 8 * (((c >> 3) ^ (r & 3) ^ (r >> 2)) & 3);
}
// [R][64] bf16 tile
__device__ inline int adr64(int r, int c) {
  return r * 64 + (c & 7) + 8 * (((c >> 3) ^ r) & 7);
}
// [64][128] bf16 tile (ot)
__device__ inline int adr128(int r, int c) {
  return r * 128 + (c & 7) + 8 * (((c >> 3) ^ (r & 7)) & 15);
}

__global__ __launch_bounds__(256, 4) void swin_mfma(
    const float* __restrict__ xin,    // [64][3136][128] f32
    const float* __restrict__ qkvb,   // [384]
    const float* __restrict__ projb,  // [128]
    const u16*  __restrict__ wq,      // [384][128] bf16
    const u16*  __restrict__ wp,      // [128][128] bf16
    const u16*  __restrict__ btab,    // [4][4][64][64] bf16
    float* __restrict__ outp)         // [64][3136][128] f32
{
  __shared__ u16 smem[10240];             // 20.5 KB total
  u16* Qh   = smem;                       // [64][32]
  u16* Kh   = smem + 2048;                // [64][32]
  u16* VTh  = smem + 4096;                // [32][64]  (row = d, col = token)
  u16* atts = smem + 6144;                // [64][64]
  // ot aliases smem[0:8192) = [64][128] after the head loop.

  const int tid  = threadIdx.x;
  const int wb   = blockIdx.x;
  const int bb   = wb >> 6, wy = (wb >> 3) & 7, wx = wb & 7;
  const int wave = tid >> 6, lane = tid & 63;
  const int g    = lane >> 4, lj = lane & 15;
  const int cls  = ((wy == 7) ? 2 : 0) | ((wx == 7) ? 1 : 0);

  // per-lane geometry (pure VALU, no LDS)
  auto gposf = [&](int tok) -> int {
    int t  = (tok < NTOK) ? tok : 0;
    int ti = div7(t), tj = t - ti * 7;
    int gh = wy * 7 + ti + 3; if (gh >= IMG) gh -= IMG;
    int gw = wx * 7 + tj + 3; if (gw >= IMG) gw -= IMG;
    return gh * IMG + gw;
  };

  const float* xb = xin + (size_t)bb * (IMG * IMG * CDIM);
  const int  arow    = 16 * wave + lj;           // A-fragment row this lane serves
  const bool arow_ok = (arow < NTOK);
  const float* xrow  = xb + (size_t)gposf(arow) * CDIM;
  int gposc[4];
  #pragma unroll
  for (int r2 = 0; r2 < 4; ++r2) gposc[r2] = gposf(16 * wave + 4 * g + r2);

  // X A-fragments: load once, keep bf16 in regs (16 VGPR)
  s16x8 afr[4];
  #pragma unroll
  for (int ks = 0; ks < 4; ++ks) {
    s16x8 r = {0, 0, 0, 0, 0, 0, 0, 0};
    if (arow_ok) {
      float4 a = *reinterpret_cast<const float4*>(xrow + 32 * ks + 8 * g);
      float4 b = *reinterpret_cast<const float4*>(xrow + 32 * ks + 8 * g + 4);
      r[0] = (short)f2bf(a.x); r[1] = (short)f2bf(a.y);
      r[2] = (short)f2bf(a.z); r[3] = (short)f2bf(a.w);
      r[4] = (short)f2bf(b.x); r[5] = (short)f2bf(b.y);
      r[6] = (short)f2bf(b.z); r[7] = (short)f2bf(b.w);
    }
    afr[ks] = r;
  }

  f32x4 pv[NHEAD][2];
  #pragma unroll
  for (int h = 0; h < NHEAD; ++h)
    #pragma unroll
    for (int jt = 0; jt < 2; ++jt) pv[h][jt] = (f32x4){0.f, 0.f, 0.f, 0.f};

  #pragma unroll
  for (int h = 0; h < NHEAD; ++h) {
    // ---- QKV GEMM for head h: this wave computes rows 16w..16w+15, 96 cols ----
    f32x4 acc[6];
    #pragma unroll
    for (int t = 0; t < 6; ++t) acc[t] = (f32x4){0.f, 0.f, 0.f, 0.f};
    #pragma unroll
    for (int ks = 0; ks < 4; ++ks) {
      #pragma unroll
      for (int t = 0; t < 6; ++t) {
        int s = t >> 1, jj = t & 1;
        int row0 = s * 128 + 32 * h + 16 * jj;
        s16x8 bfr = *reinterpret_cast<const s16x8*>(
            &wq[(size_t)(row0 + lj) * 128 + 32 * ks + 8 * g]);
        acc[t] = __builtin_amdgcn_mfma_f32_16x16x32_bf16(afr[ks], bfr, acc[t], 0, 0, 0);
      }
    }
    #pragma unroll
    for (int t = 0; t < 6; ++t) {
      int s = t >> 1, jj = t & 1;
      int col = 16 * jj + lj;                 // 0..31 within head section
      float bias = qkvb[s * 128 + 32 * h + col];
      #pragma unroll
      for (int r2 = 0; r2 < 4; ++r2) {
        int tok = 16 * wave + 4 * g + r2;
        float val = acc[t][r2] + bias;
        if (s == 0)      Qh[adr32(tok, col)] = f2bf(val * QSCALE);
        else if (s == 1) Kh[adr32(tok, col)] = f2bf(val);
        else             VTh[adr64(col, tok)] = f2bf(val);
      }
    }
    __syncthreads();

    // ---- QK^T (hd=32 -> single k-step) ----
    s16x8 qa = *reinterpret_cast<const s16x8*>(&Qh[adr32(16 * wave + lj, 8 * g)]);
    f32x4 qk[4];
    #pragma unroll
    for (int jt = 0; jt < 4; ++jt) {
      s16x8 kb = *reinterpret_cast<const s16x8*>(&Kh[adr32(16 * jt + lj, 8 * g)]);
      qk[jt] = __builtin_amdgcn_mfma_f32_16x16x32_bf16(
          qa, kb, (f32x4){0.f, 0.f, 0.f, 0.f}, 0, 0, 0);
    }
    // bias+mask+pad from table (coalesced L2 loads)
    const u16* bt = btab + (((cls << 2) + h) << 12);
    float mx[4] = {-3e38f, -3e38f, -3e38f, -3e38f};
    #pragma unroll
    for (int jt = 0; jt < 4; ++jt) {
      #pragma unroll
      for (int r2 = 0; r2 < 4; ++r2) {
        int n = 16 * wave + 4 * g + r2, m = 16 * jt + lj;
        float s = qk[jt][r2] + bf2f(bt[(n << 6) + m]);
        qk[jt][r2] = s;
        mx[r2] = fmaxf(mx[r2], s);
      }
    }
    // wave-parallel softmax across the 16 lanes of each row
    #pragma unroll
    for (int r2 = 0; r2 < 4; ++r2)
      #pragma unroll
      for (int off = 8; off >= 1; off >>= 1)
        mx[r2] = fmaxf(mx[r2], __shfl_xor(mx[r2], off, 64));
    float sm[4] = {0.f, 0.f, 0.f, 0.f};
    #pragma unroll
    for (int jt = 0; jt < 4; ++jt)
      #pragma unroll
      for (int r2 = 0; r2 < 4; ++r2) {
        float e = __expf(qk[jt][r2] - mx[r2]);
        qk[jt][r2] = e;
        sm[r2] += e;
      }
    #pragma unroll
    for (int r2 = 0; r2 < 4; ++r2) {
      #pragma unroll
      for (int off = 8; off >= 1; off >>= 1)
        sm[r2] += __shfl_xor(sm[r2], off, 64);
      sm[r2] = 1.f / sm[r2];
    }
    #pragma unroll
    for (int jt = 0; jt < 4; ++jt)
      #pragma unroll
      for (int r2 = 0; r2 < 4; ++r2) {
        int n = 16 * wave + 4 * g + r2, m = 16 * jt + lj;
        atts[adr64(n, m)] = f2bf(qk[jt][r2] * sm[r2]);
      }

    // ---- PV (atts rows are this wave's own; no barrier needed before read) ----
    #pragma unroll
    for (int ks2 = 0; ks2 < 2; ++ks2) {
      s16x8 pa = *reinterpret_cast<const s16x8*>(
          &atts[adr64(16 * wave + lj, 32 * ks2 + 8 * g)]);
      #pragma unroll
      for (int jt = 0; jt < 2; ++jt) {
        s16x8 vb = *reinterpret_cast<const s16x8*>(
            &VTh[adr64(16 * jt + lj, 32 * ks2 + 8 * g)]);
        pv[h][jt] = __builtin_amdgcn_mfma_f32_16x16x32_bf16(pa, vb, pv[h][jt], 0, 0, 0);
      }
    }
    __syncthreads();   // protect Qh/Kh/VTh/atts before next head overwrites
  }

  // ---- attention output -> LDS (aliases Qh/Kh/VTh/atts region) ----
  #pragma unroll
  for (int h = 0; h < NHEAD; ++h)
    #pragma unroll
    for (int jt = 0; jt < 2; ++jt)
      #pragma unroll
      for (int r2 = 0; r2 < 4; ++r2) {
        int tok = 16 * wave + 4 * g + r2;
        int c   = 32 * h + 16 * jt + lj;
        smem[adr128(tok, c)] = f2bf(pv[h][jt][r2]);
      }
  __syncthreads();

  // ---- projection + scatter ----
  f32x4 pr[8];
  #pragma unroll
  for (int jt = 0; jt < 8; ++jt) pr[jt] = (f32x4){0.f, 0.f, 0.f, 0.f};
  #pragma unroll
  for (int ks = 0; ks < 4; ++ks) {
    s16x8 pa = *reinterpret_cast<const s16x8*>(&smem[adr128(16 * wave + lj, 32 * ks + 8 * g)]);
    #pragma unroll
    for (int jt = 0; jt < 8; ++jt) {
      s16x8 pb = *reinterpret_cast<const s16x8*>(
          &wp[(size_t)(16 * jt + lj) * 128 + 32 * ks + 8 * g]);
      pr[jt] = __builtin_amdgcn_mfma_f32_16x16x32_bf16(pa, pb, pr[jt], 0, 0, 0);
    }
  }
  float* ob = outp + (size_t)bb * (IMG * IMG * CDIM);
  #pragma unroll
  for (int jt = 0; jt < 8; ++jt) {
    float bias = projb[16 * jt + lj];
    #pragma unroll
    for (int r2 = 0; r2 < 4; ++r2) {
      int tok = 16 * wave + 4 * g + r2;
      if (tok < NTOK)
        ob[(size_t)gposc[r2] * CDIM + 16 * jt + lj] = pr[jt][r2] + bias;
    }
  }
}

}  // namespace

extern "C" void kernel_launch(void* const* d_in, const int* in_sizes, int n_in,
                              void* d_out, int out_size, void* d_ws, size_t ws_size,
                              hipStream_t stream) {
  const float* x     = (const float*)d_in[0];
  const float* rpb   = (const float*)d_in[1];
  const float* qkvw  = (const float*)d_in[2];
  const float* qkvb  = (const float*)d_in[3];
  const float* projw = (const float*)d_in[4];
  const float* projb = (const float*)d_in[5];
  u16* wq   = (u16*)d_ws;                 // 384*128
  u16* wp   = wq + 384 * 128;             // 128*128
  u16* btab = wp + 128 * 128;             // 4*4*64*64

  prep<<<256, 256, 0, stream>>>(qkvw, projw, rpb, wq, wp, btab);
  swin_mfma<<<NBLK, 256, 0, stream>>>(x, qkvb, projb, wq, wp, btab, (float*)d_out);
}

// Round 4
// 355.838 us; speedup vs baseline: 1.0285x; 1.0285x over previous
//
#include <hip/hip_runtime.h>

typedef short s16x8 __attribute__((ext_vector_type(8)));
typedef float f32x4 __attribute__((ext_vector_type(4)));
typedef unsigned short u16;

namespace {

constexpr int NHEAD = 4;
constexpr int CDIM  = 128;
constexpr int NTOK  = 49;
constexpr int IMG   = 56;
constexpr int NBLK  = 4096;
constexpr float QSCALE = 0.17677669529663687f;  // 32^-0.5

__device__ inline u16 f2bf(float x) {
  unsigned u = __float_as_uint(x);
  u += 0x7fffu + ((u >> 16) & 1u);
  return (u16)(u >> 16);
}
__device__ inline float bf2f(u16 h) { return __uint_as_float(((unsigned)h) << 16); }
__device__ inline int div7(int t) { return (t * 9363) >> 16; }  // valid t<64

// ---- prep: bf16 weights + combined bias/mask/pad table (all L2-resident) ----
__global__ void prep(const float* __restrict__ qkvw, const float* __restrict__ projw,
                     const float* __restrict__ rpb,
                     u16* __restrict__ wq, u16* __restrict__ wp, u16* __restrict__ btab) {
  int i = blockIdx.x * 256 + threadIdx.x;
  if (i < 384 * 128) wq[i] = f2bf(qkvw[i]);
  if (i < 128 * 128) wp[i] = f2bf(projw[i]);
  if (i < 65536) {
    int m = i & 63, n = (i >> 6) & 63, h = (i >> 12) & 3, cls = (i >> 14) & 3;
    float v;
    if (m >= NTOK) v = -1e9f;
    else if (n >= NTOK) v = 0.f;
    else {
      int tin = div7(n), tjn = n - tin * 7;
      int tim = div7(m), tjm = m - tim * 7;
      int ridx = 13 * (tin - tim + 6) + (tjn - tjm + 6);
      v = rpb[ridx * NHEAD + h];
      int wy = (cls & 2) ? 7 : 0, wx = (cls & 1) ? 7 : 0;
      int mhn = wy * 7 + tin, mwn = wx * 7 + tjn;
      int mhm = wy * 7 + tim, mwm = wx * 7 + tjm;
      int cn = ((mhn < 49) ? 0 : ((mhn < 53) ? 1 : 2)) * 3 + ((mwn < 49) ? 0 : ((mwn < 53) ? 1 : 2));
      int cm = ((mhm < 49) ? 0 : ((mhm < 53) ? 1 : 2)) * 3 + ((mwm < 49) ? 0 : ((mwm < 53) ? 1 : 2));
      if (cn != cm) v -= 100.f;
    }
    btab[i] = f2bf(v);
  }
}

// LDS swizzles (write and read agree; reads are 16B-aligned ds_read_b128):
__device__ inline int adr32(int r, int c) {
  return r * 32 + (c & 7) + 8 * (((c >> 3) ^ (r & 3) ^ (r >> 2)) & 3);
}
__device__ inline int adr64(int r, int c) {
  return r * 64 + (c & 7) + 8 * (((c >> 3) ^ r) & 7);
}
__device__ inline int adr128(int r, int c) {
  return r * 128 + (c & 7) + 8 * (((c >> 3) ^ (r & 7)) & 15);
}

__global__ __launch_bounds__(256, 2) void swin_mfma(
    const float* __restrict__ xin,    // [64][3136][128] f32
    const float* __restrict__ qkvb,   // [384]
    const float* __restrict__ projb,  // [128]
    const u16*  __restrict__ wq,      // [384][128] bf16
    const u16*  __restrict__ wp,      // [128][128] bf16
    const u16*  __restrict__ btab,    // [4][4][64][64] bf16
    float* __restrict__ outp)         // [64][3136][128] f32
{
  __shared__ u16 Qh[2048];    // [64][32]
  __shared__ u16 Kh[2048];    // [64][32]
  __shared__ u16 VTh[2048];   // [32][64] (row=d, col=token)
  __shared__ u16 atts[4096];  // [64][64]
  __shared__ u16 ot[8192];    // [64][128] attention output (bf16)

  const int tid  = threadIdx.x;
  const int wb   = blockIdx.x;
  const int bb   = wb >> 6, wy = (wb >> 3) & 7, wx = wb & 7;
  const int wave = tid >> 6, lane = tid & 63;
  const int g    = lane >> 4, lj = lane & 15;
  const int cls  = ((wy == 7) ? 2 : 0) | ((wx == 7) ? 1 : 0);

  auto gposf = [&](int tok) -> int {
    int t  = (tok < NTOK) ? tok : 0;
    int ti = div7(t), tj = t - ti * 7;
    int gh = wy * 7 + ti + 3; if (gh >= IMG) gh -= IMG;
    int gw = wx * 7 + tj + 3; if (gw >= IMG) gw -= IMG;
    return gh * IMG + gw;
  };

  const float* xb = xin + (size_t)bb * (IMG * IMG * CDIM);
  const int  arow    = 16 * wave + lj;
  const bool arow_ok = (arow < NTOK);
  const float* xrow  = xb + (size_t)gposf(arow) * CDIM;

  // X A-fragments: load once, keep bf16 in regs (16 VGPR)
  s16x8 afr[4];
  #pragma unroll
  for (int ks = 0; ks < 4; ++ks) {
    s16x8 r = {0, 0, 0, 0, 0, 0, 0, 0};
    if (arow_ok) {
      float4 a = *reinterpret_cast<const float4*>(xrow + 32 * ks + 8 * g);
      float4 b = *reinterpret_cast<const float4*>(xrow + 32 * ks + 8 * g + 4);
      r[0] = (short)f2bf(a.x); r[1] = (short)f2bf(a.y);
      r[2] = (short)f2bf(a.z); r[3] = (short)f2bf(a.w);
      r[4] = (short)f2bf(b.x); r[5] = (short)f2bf(b.y);
      r[6] = (short)f2bf(b.z); r[7] = (short)f2bf(b.w);
    }
    afr[ks] = r;
  }

  #pragma unroll
  for (int h = 0; h < NHEAD; ++h) {
    // ---- QKV GEMM for head h: rows 16w..16w+15, 96 cols (Q,K,V x 32) ----
    f32x4 acc[6];
    #pragma unroll
    for (int t = 0; t < 6; ++t) acc[t] = (f32x4){0.f, 0.f, 0.f, 0.f};
    #pragma unroll
    for (int ks = 0; ks < 4; ++ks) {
      #pragma unroll
      for (int t = 0; t < 6; ++t) {
        int s = t >> 1, jj = t & 1;
        int row0 = s * 128 + 32 * h + 16 * jj;
        s16x8 bfr = *reinterpret_cast<const s16x8*>(
            &wq[(size_t)(row0 + lj) * 128 + 32 * ks + 8 * g]);
        acc[t] = __builtin_amdgcn_mfma_f32_16x16x32_bf16(afr[ks], bfr, acc[t], 0, 0, 0);
      }
    }
    #pragma unroll
    for (int t = 0; t < 6; ++t) {
      int s = t >> 1, jj = t & 1;
      int col = 16 * jj + lj;
      float bias = qkvb[s * 128 + 32 * h + col];
      #pragma unroll
      for (int r2 = 0; r2 < 4; ++r2) {
        int tok = 16 * wave + 4 * g + r2;
        float val = acc[t][r2] + bias;
        if (s == 0)      Qh[adr32(tok, col)] = f2bf(val * QSCALE);
        else if (s == 1) Kh[adr32(tok, col)] = f2bf(val);
        else             VTh[adr64(col, tok)] = f2bf(val);
      }
    }
    __syncthreads();

    // ---- hoisted bias/mask table loads (independent of MFMA -> hide latency)
    const u16* bt = btab + (((cls << 2) + h) << 12);
    float bval[4][4];
    #pragma unroll
    for (int jt = 0; jt < 4; ++jt)
      #pragma unroll
      for (int r2 = 0; r2 < 4; ++r2) {
        int n = 16 * wave + 4 * g + r2, m = 16 * jt + lj;
        bval[jt][r2] = bf2f(bt[(n << 6) + m]);
      }

    // ---- QK^T (hd=32 -> single k-step) ----
    s16x8 qa = *reinterpret_cast<const s16x8*>(&Qh[adr32(16 * wave + lj, 8 * g)]);
    f32x4 qk[4];
    #pragma unroll
    for (int jt = 0; jt < 4; ++jt) {
      s16x8 kb = *reinterpret_cast<const s16x8*>(&Kh[adr32(16 * jt + lj, 8 * g)]);
      qk[jt] = __builtin_amdgcn_mfma_f32_16x16x32_bf16(
          qa, kb, (f32x4){0.f, 0.f, 0.f, 0.f}, 0, 0, 0);
    }
    float mx[4] = {-3e38f, -3e38f, -3e38f, -3e38f};
    #pragma unroll
    for (int jt = 0; jt < 4; ++jt)
      #pragma unroll
      for (int r2 = 0; r2 < 4; ++r2) {
        float s = qk[jt][r2] + bval[jt][r2];
        qk[jt][r2] = s;
        mx[r2] = fmaxf(mx[r2], s);
      }
    #pragma unroll
    for (int r2 = 0; r2 < 4; ++r2)
      #pragma unroll
      for (int off = 8; off >= 1; off >>= 1)
        mx[r2] = fmaxf(mx[r2], __shfl_xor(mx[r2], off, 64));
    float sm[4] = {0.f, 0.f, 0.f, 0.f};
    #pragma unroll
    for (int jt = 0; jt < 4; ++jt)
      #pragma unroll
      for (int r2 = 0; r2 < 4; ++r2) {
        float e = __expf(qk[jt][r2] - mx[r2]);
        qk[jt][r2] = e;
        sm[r2] += e;
      }
    #pragma unroll
    for (int r2 = 0; r2 < 4; ++r2) {
      #pragma unroll
      for (int off = 8; off >= 1; off >>= 1)
        sm[r2] += __shfl_xor(sm[r2], off, 64);
      sm[r2] = 1.f / sm[r2];
    }
    #pragma unroll
    for (int jt = 0; jt < 4; ++jt)
      #pragma unroll
      for (int r2 = 0; r2 < 4; ++r2) {
        int n = 16 * wave + 4 * g + r2, m = 16 * jt + lj;
        atts[adr64(n, m)] = f2bf(qk[jt][r2] * sm[r2]);
      }

    // ---- PV (atts rows are this wave's own; VTh synced by earlier barrier) ----
    f32x4 pv[2] = {(f32x4){0.f, 0.f, 0.f, 0.f}, (f32x4){0.f, 0.f, 0.f, 0.f}};
    #pragma unroll
    for (int ks2 = 0; ks2 < 2; ++ks2) {
      s16x8 pa = *reinterpret_cast<const s16x8*>(
          &atts[adr64(16 * wave + lj, 32 * ks2 + 8 * g)]);
      #pragma unroll
      for (int jt = 0; jt < 2; ++jt) {
        s16x8 vb = *reinterpret_cast<const s16x8*>(
            &VTh[adr64(16 * jt + lj, 32 * ks2 + 8 * g)]);
        pv[jt] = __builtin_amdgcn_mfma_f32_16x16x32_bf16(pa, vb, pv[jt], 0, 0, 0);
      }
    }
    // write this head's output slice to ot (wave-exclusive rows)
    #pragma unroll
    for (int jt = 0; jt < 2; ++jt)
      #pragma unroll
      for (int r2 = 0; r2 < 4; ++r2) {
        int tok = 16 * wave + 4 * g + r2;
        int c   = 32 * h + 16 * jt + lj;
        ot[adr128(tok, c)] = f2bf(pv[jt][r2]);
      }
    __syncthreads();   // protect Qh/Kh/VTh before next head overwrites
  }

  // ---- projection + scatter ----
  f32x4 pr[8];
  #pragma unroll
  for (int jt = 0; jt < 8; ++jt) pr[jt] = (f32x4){0.f, 0.f, 0.f, 0.f};
  #pragma unroll
  for (int ks = 0; ks < 4; ++ks) {
    s16x8 pa = *reinterpret_cast<const s16x8*>(&ot[adr128(16 * wave + lj, 32 * ks + 8 * g)]);
    #pragma unroll
    for (int jt = 0; jt < 8; ++jt) {
      s16x8 pb = *reinterpret_cast<const s16x8*>(
          &wp[(size_t)(16 * jt + lj) * 128 + 32 * ks + 8 * g]);
      pr[jt] = __builtin_amdgcn_mfma_f32_16x16x32_bf16(pa, pb, pr[jt], 0, 0, 0);
    }
  }
  float* ob = outp + (size_t)bb * (IMG * IMG * CDIM);
  #pragma unroll
  for (int jt = 0; jt < 8; ++jt) {
    float bias = projb[16 * jt + lj];
    #pragma unroll
    for (int r2 = 0; r2 < 4; ++r2) {
      int tok = 16 * wave + 4 * g + r2;
      if (tok < NTOK)
        ob[(size_t)gposf(tok) * CDIM + 16 * jt + lj] = pr[jt][r2] + bias;
    }
  }
}

}  // namespace

extern "C" void kernel_launch(void* const* d_in, const int* in_sizes, int n_in,
                              void* d_out, int out_size, void* d_ws, size_t ws_size,
                              hipStream_t stream) {
  const float* x     = (const float*)d_in[0];
  const float* rpb   = (const float*)d_in[1];
  const float* qkvw  = (const float*)d_in[2];
  const float* qkvb  = (const float*)d_in[3];
  const float* projw = (const float*)d_in[4];
  const float* projb = (const float*)d_in[5];
  u16* wq   = (u16*)d_ws;                 // 384*128
  u16* wp   = wq + 384 * 128;             // 128*128
  u16* btab = wp + 128 * 128;             // 4*4*64*64

  prep<<<256, 256, 0, stream>>>(qkvw, projw, rpb, wq, wp, btab);
  swin_mfma<<<NBLK, 256, 0, stream>>>(x, qkvb, projb, wq, wp, btab, (float*)d_out);
}

// Round 5
// 300.132 us; speedup vs baseline: 1.2194x; 1.1856x over previous
//
#include <hip/hip_runtime.h>

typedef short s16x8 __attribute__((ext_vector_type(8)));
typedef float f32x4 __attribute__((ext_vector_type(4)));
typedef unsigned short u16;

namespace {

constexpr int NHEAD = 4;
constexpr int CDIM  = 128;
constexpr int NTOK  = 49;
constexpr int IMG   = 56;
constexpr int NBLK  = 4096;
constexpr float QSCALE = 0.17677669529663687f;  // 32^-0.5

__device__ inline u16 f2bf(float x) {
  unsigned u = __float_as_uint(x);
  u += 0x7fffu + ((u >> 16) & 1u);
  return (u16)(u >> 16);
}
__device__ inline float bf2f(u16 h) { return __uint_as_float(((unsigned)h) << 16); }
__device__ inline int div7(int t) { return (t * 9363) >> 16; }  // valid t<64

// ---- prep: bf16 weights + combined bias/mask/pad table (all L2-resident) ----
__global__ void prep(const float* __restrict__ qkvw, const float* __restrict__ projw,
                     const float* __restrict__ rpb,
                     u16* __restrict__ wq, u16* __restrict__ wp, u16* __restrict__ btab) {
  int i = blockIdx.x * 256 + threadIdx.x;
  if (i < 384 * 128) wq[i] = f2bf(qkvw[i]);
  if (i < 128 * 128) wp[i] = f2bf(projw[i]);
  if (i < 65536) {
    int m = i & 63, n = (i >> 6) & 63, h = (i >> 12) & 3, cls = (i >> 14) & 3;
    float v;
    if (m >= NTOK) v = -1e9f;
    else if (n >= NTOK) v = 0.f;
    else {
      int tin = div7(n), tjn = n - tin * 7;
      int tim = div7(m), tjm = m - tim * 7;
      int ridx = 13 * (tin - tim + 6) + (tjn - tjm + 6);
      v = rpb[ridx * NHEAD + h];
      int wy = (cls & 2) ? 7 : 0, wx = (cls & 1) ? 7 : 0;
      int mhn = wy * 7 + tin, mwn = wx * 7 + tjn;
      int mhm = wy * 7 + tim, mwm = wx * 7 + tjm;
      int cn = ((mhn < 49) ? 0 : ((mhn < 53) ? 1 : 2)) * 3 + ((mwn < 49) ? 0 : ((mwn < 53) ? 1 : 2));
      int cm = ((mhm < 49) ? 0 : ((mhm < 53) ? 1 : 2)) * 3 + ((mwm < 49) ? 0 : ((mwm < 53) ? 1 : 2));
      if (cn != cm) v -= 100.f;
    }
    btab[i] = f2bf(v);
  }
}

// LDS swizzles (write/read agree; fragment reads are 16B-aligned ds_read_b128):
__device__ inline int adr128(int r, int c) {
  return r * 128 + (c & 7) + 8 * (((c >> 3) ^ (r & 7)) & 15);
}
__device__ inline int adr64(int r, int c) {
  return r * 64 + (c & 7) + 8 * (((c >> 3) ^ r) & 7);
}
__device__ inline int adr32(int r, int c) {
  return r * 32 + (c & 7) + 8 * (((c >> 3) ^ (r & 3) ^ (r >> 2)) & 3);
}

__global__ __launch_bounds__(256, 2) void swin_mfma(
    const float* __restrict__ xin,    // [64][3136][128] f32
    const float* __restrict__ qkvb,   // [384]
    const float* __restrict__ projb,  // [128]
    const u16*  __restrict__ wq,      // [384][128] bf16
    const u16*  __restrict__ wp,      // [128][128] bf16
    const u16*  __restrict__ btab,    // [4][4][64][64] bf16
    float* __restrict__ outp)         // [64][3136][128] f32
{
  __shared__ u16 Qs[8192];    // [64][128]
  __shared__ u16 Ks[8192];    // [64][128]
  __shared__ u16 VTs[8192];   // [128][64] (row=d, col=token)
  __shared__ u16 atts[4096];  // [64][64]  (wave-private 16-row strips)
  __shared__ u16 obuf[2048];  // [64][32]  (wave-private 16-row strips)

  const int tid  = threadIdx.x;
  const int wb   = blockIdx.x;
  const int bb   = wb >> 6, wy = (wb >> 3) & 7, wx = wb & 7;
  const int wave = tid >> 6, lane = tid & 63;
  const int g    = lane >> 4, lj = lane & 15;
  const int cls  = ((wy == 7) ? 2 : 0) | ((wx == 7) ? 1 : 0);

  auto gposf = [&](int tok) -> int {
    int t  = (tok < NTOK) ? tok : 0;
    int ti = div7(t), tj = t - ti * 7;
    int gh = wy * 7 + ti + 3; if (gh >= IMG) gh -= IMG;
    int gw = wx * 7 + tj + 3; if (gw >= IMG) gw -= IMG;
    return gh * IMG + gw;
  };

  const float* xb = xin + (size_t)bb * (IMG * IMG * CDIM);
  const int  arow    = 16 * wave + lj;
  const bool arow_ok = (arow < NTOK);
  const float* xrow  = xb + (size_t)gposf(arow) * CDIM;
  int gposc[4];
  #pragma unroll
  for (int r2 = 0; r2 < 4; ++r2) gposc[r2] = gposf(16 * wave + 4 * g + r2);

  // X A-fragments for this wave's 16 rows (16 VGPR, loaded once)
  s16x8 afr[4];
  #pragma unroll
  for (int ks = 0; ks < 4; ++ks) {
    s16x8 r = {0, 0, 0, 0, 0, 0, 0, 0};
    if (arow_ok) {
      float4 a = *reinterpret_cast<const float4*>(xrow + 32 * ks + 8 * g);
      float4 b = *reinterpret_cast<const float4*>(xrow + 32 * ks + 8 * g + 4);
      r[0] = (short)f2bf(a.x); r[1] = (short)f2bf(a.y);
      r[2] = (short)f2bf(a.z); r[3] = (short)f2bf(a.w);
      r[4] = (short)f2bf(b.x); r[5] = (short)f2bf(b.y);
      r[6] = (short)f2bf(b.z); r[7] = (short)f2bf(b.w);
    }
    afr[ks] = r;
  }

  // ---- QKV GEMM, row-strip: wave w -> rows 16w..16w+15, all 384 cols ----
  // Per-tile retire keeps only one f32x4 acc live -> low VGPR pressure.
  #pragma unroll
  for (int t = 0; t < 24; ++t) {
    f32x4 acc = (f32x4){0.f, 0.f, 0.f, 0.f};
    #pragma unroll
    for (int ks = 0; ks < 4; ++ks) {
      s16x8 bfr = *reinterpret_cast<const s16x8*>(
          &wq[(size_t)(16 * t + lj) * 128 + 32 * ks + 8 * g]);
      acc = __builtin_amdgcn_mfma_f32_16x16x32_bf16(afr[ks], bfr, acc, 0, 0, 0);
    }
    float bias = qkvb[16 * t + lj];
    const int sec = t >> 3;                 // 0=Q 1=K 2=V
    const int c   = (16 * t + lj) & 127;
    #pragma unroll
    for (int r2 = 0; r2 < 4; ++r2) {
      int tok = 16 * wave + 4 * g + r2;
      float val = acc[r2] + bias;
      if (sec == 0)      Qs[adr128(tok, c)] = f2bf(val * QSCALE);
      else if (sec == 1) Ks[adr128(tok, c)] = f2bf(val);
      else               VTs[adr64(c, tok)] = f2bf(val);
    }
  }
  __syncthreads();   // THE ONLY BARRIER: K/VT become visible cross-wave

  f32x4 pr[8];
  #pragma unroll
  for (int jt = 0; jt < 8; ++jt) pr[jt] = (f32x4){0.f, 0.f, 0.f, 0.f};

  #pragma unroll
  for (int h = 0; h < NHEAD; ++h) {
    // hoisted bias/mask table loads (L2, independent of MFMA below)
    const u16* bt = btab + (((cls << 2) + h) << 12);
    float bval[4][4];
    #pragma unroll
    for (int jt = 0; jt < 4; ++jt)
      #pragma unroll
      for (int r2 = 0; r2 < 4; ++r2) {
        int n = 16 * wave + 4 * g + r2, m = 16 * jt + lj;
        bval[jt][r2] = bf2f(bt[(n << 6) + m]);
      }

    // ---- QK^T (hd=32 -> single k-step) ----
    s16x8 qa = *reinterpret_cast<const s16x8*>(&Qs[adr128(16 * wave + lj, 32 * h + 8 * g)]);
    f32x4 qk[4];
    #pragma unroll
    for (int jt = 0; jt < 4; ++jt) {
      s16x8 kb = *reinterpret_cast<const s16x8*>(&Ks[adr128(16 * jt + lj, 32 * h + 8 * g)]);
      qk[jt] = __builtin_amdgcn_mfma_f32_16x16x32_bf16(
          qa, kb, (f32x4){0.f, 0.f, 0.f, 0.f}, 0, 0, 0);
    }
    float mx[4] = {-3e38f, -3e38f, -3e38f, -3e38f};
    #pragma unroll
    for (int jt = 0; jt < 4; ++jt)
      #pragma unroll
      for (int r2 = 0; r2 < 4; ++r2) {
        float s = qk[jt][r2] + bval[jt][r2];
        qk[jt][r2] = s;
        mx[r2] = fmaxf(mx[r2], s);
      }
    // wave-parallel softmax across the 16 lanes holding each row
    #pragma unroll
    for (int r2 = 0; r2 < 4; ++r2)
      #pragma unroll
      for (int off = 8; off >= 1; off >>= 1)
        mx[r2] = fmaxf(mx[r2], __shfl_xor(mx[r2], off, 64));
    float sm[4] = {0.f, 0.f, 0.f, 0.f};
    #pragma unroll
    for (int jt = 0; jt < 4; ++jt)
      #pragma unroll
      for (int r2 = 0; r2 < 4; ++r2) {
        float e = __expf(qk[jt][r2] - mx[r2]);
        qk[jt][r2] = e;
        sm[r2] += e;
      }
    #pragma unroll
    for (int r2 = 0; r2 < 4; ++r2) {
      #pragma unroll
      for (int off = 8; off >= 1; off >>= 1)
        sm[r2] += __shfl_xor(sm[r2], off, 64);
      sm[r2] = 1.f / sm[r2];
    }
    #pragma unroll
    for (int jt = 0; jt < 4; ++jt)
      #pragma unroll
      for (int r2 = 0; r2 < 4; ++r2) {
        int n = 16 * wave + 4 * g + r2, m = 16 * jt + lj;
        atts[adr64(n, m)] = f2bf(qk[jt][r2] * sm[r2]);
      }

    // ---- PV (atts rows wave-private; VTs read-only since barrier) ----
    f32x4 pv[2] = {(f32x4){0.f, 0.f, 0.f, 0.f}, (f32x4){0.f, 0.f, 0.f, 0.f}};
    #pragma unroll
    for (int ks2 = 0; ks2 < 2; ++ks2) {
      s16x8 pa = *reinterpret_cast<const s16x8*>(
          &atts[adr64(16 * wave + lj, 32 * ks2 + 8 * g)]);
      #pragma unroll
      for (int jt = 0; jt < 2; ++jt) {
        s16x8 vb = *reinterpret_cast<const s16x8*>(
            &VTs[adr64(32 * h + 16 * jt + lj, 32 * ks2 + 8 * g)]);
        pv[jt] = __builtin_amdgcn_mfma_f32_16x16x32_bf16(pa, vb, pv[jt], 0, 0, 0);
      }
    }

    // ---- fused proj partial: pv -> obuf (wave-private) -> A-frag -> pr ----
    #pragma unroll
    for (int jt = 0; jt < 2; ++jt)
      #pragma unroll
      for (int r2 = 0; r2 < 4; ++r2)
        obuf[adr32(16 * wave + 4 * g + r2, 16 * jt + lj)] = f2bf(pv[jt][r2]);
    s16x8 oa = *reinterpret_cast<const s16x8*>(&obuf[adr32(16 * wave + lj, 8 * g)]);
    #pragma unroll
    for (int jt = 0; jt < 8; ++jt) {
      s16x8 pb = *reinterpret_cast<const s16x8*>(
          &wp[(size_t)(16 * jt + lj) * 128 + 32 * h + 8 * g]);
      pr[jt] = __builtin_amdgcn_mfma_f32_16x16x32_bf16(oa, pb, pr[jt], 0, 0, 0);
    }
  }

  // ---- output store (roll-reverse scatter) ----
  float* ob = outp + (size_t)bb * (IMG * IMG * CDIM);
  #pragma unroll
  for (int jt = 0; jt < 8; ++jt) {
    float bias = projb[16 * jt + lj];
    #pragma unroll
    for (int r2 = 0; r2 < 4; ++r2) {
      int tok = 16 * wave + 4 * g + r2;
      if (tok < NTOK)
        ob[(size_t)gposc[r2] * CDIM + 16 * jt + lj] = pr[jt][r2] + bias;
    }
  }
}

}  // namespace

extern "C" void kernel_launch(void* const* d_in, const int* in_sizes, int n_in,
                              void* d_out, int out_size, void* d_ws, size_t ws_size,
                              hipStream_t stream) {
  const float* x     = (const float*)d_in[0];
  const float* rpb   = (const float*)d_in[1];
  const float* qkvw  = (const float*)d_in[2];
  const float* qkvb  = (const float*)d_in[3];
  const float* projw = (const float*)d_in[4];
  const float* projb = (const float*)d_in[5];
  u16* wq   = (u16*)d_ws;                 // 384*128
  u16* wp   = wq + 384 * 128;             // 128*128
  u16* btab = wp + 128 * 128;             // 4*4*64*64

  prep<<<256, 256, 0, stream>>>(qkvw, projw, rpb, wq, wp, btab);
  swin_mfma<<<NBLK, 256, 0, stream>>>(x, qkvb, projb, wq, wp, btab, (float*)d_out);
}

// Round 6
// 150.481 us; speedup vs baseline: 2.4320x; 1.9945x over previous
//
#include <hip/hip_runtime.h>

typedef short s16x8 __attribute__((ext_vector_type(8)));
typedef short s16x4 __attribute__((ext_vector_type(4)));
typedef float f32x4 __attribute__((ext_vector_type(4)));
typedef unsigned short u16;

namespace {

constexpr int NHEAD = 4;
constexpr int CDIM  = 128;
constexpr int NTOK  = 49;
constexpr int IMG   = 56;
constexpr int NWIN  = 4096;   // 64 batches x 8x8 windows; 1 wave each
constexpr float QSCALE = 0.17677669529663687f;  // 32^-0.5

__device__ inline u16 f2bf(float x) {
  unsigned u = __float_as_uint(x);
  u += 0x7fffu + ((u >> 16) & 1u);
  return (u16)(u >> 16);
}
__device__ inline float bf2f(u16 h) { return __uint_as_float(((unsigned)h) << 16); }
__device__ inline int div7(int t) { return (t * 9363) >> 16; }  // valid t<64

__device__ inline f32x4 mfma32(s16x8 a, s16x8 b, f32x4 c) {
  return __builtin_amdgcn_mfma_f32_16x16x32_bf16(a, b, c, 0, 0, 0);
}
__device__ inline f32x4 mfma16(s16x4 a, s16x4 b, f32x4 c) {
#if __has_builtin(__builtin_amdgcn_mfma_f32_16x16x16bf16_1k)
  return __builtin_amdgcn_mfma_f32_16x16x16bf16_1k(a, b, c, 0, 0, 0);
#else
  f32x4 d;
  asm volatile("v_mfma_f32_16x16x16_bf16 %0, %1, %2, %3"
               : "=v"(d) : "v"(a), "v"(b), "v"(c));
  return d;
#endif
}
__device__ inline s16x4 pack4(f32x4 v) {
  s16x4 r;
  r[0] = (short)f2bf(v[0]); r[1] = (short)f2bf(v[1]);
  r[2] = (short)f2bf(v[2]); r[3] = (short)f2bf(v[3]);
  return r;
}

// ---- prep: bf16 weights + combined bias/mask/pad table (unchanged) ----
__global__ void prep(const float* __restrict__ qkvw, const float* __restrict__ projw,
                     const float* __restrict__ rpb,
                     u16* __restrict__ wq, u16* __restrict__ wp, u16* __restrict__ btab) {
  int i = blockIdx.x * 256 + threadIdx.x;
  if (i < 384 * 128) wq[i] = f2bf(qkvw[i]);
  if (i < 128 * 128) wp[i] = f2bf(projw[i]);
  if (i < 65536) {
    int m = i & 63, n = (i >> 6) & 63, h = (i >> 12) & 3, cls = (i >> 14) & 3;
    float v;
    if (m >= NTOK) v = -1e9f;           // key-pad: excluded from softmax
    else if (n >= NTOK) v = 0.f;        // query-pad: don't-care (never stored)
    else {
      int tin = div7(n), tjn = n - tin * 7;
      int tim = div7(m), tjm = m - tim * 7;
      int ridx = 13 * (tin - tim + 6) + (tjn - tjm + 6);
      v = rpb[ridx * NHEAD + h];
      int wy = (cls & 2) ? 7 : 0, wx = (cls & 1) ? 7 : 0;
      int mhn = wy * 7 + tin, mwn = wx * 7 + tjn;
      int mhm = wy * 7 + tim, mwm = wx * 7 + tjm;
      int cn = ((mhn < 49) ? 0 : ((mhn < 53) ? 1 : 2)) * 3 + ((mwn < 49) ? 0 : ((mwn < 53) ? 1 : 2));
      int cm = ((mhm < 49) ? 0 : ((mhm < 53) ? 1 : 2)) * 3 + ((mwm < 49) ? 0 : ((mwm < 53) ? 1 : 2));
      if (cn != cm) v -= 100.f;
    }
    btab[i] = f2bf(v);
  }
}

// o_lds swizzle ([64][128] bf16): 4-element groups stay contiguous (b64 ops)
__device__ inline int adr128(int r, int c) {
  return r * 128 + (c & 7) + 8 * (((c >> 3) ^ (r & 7)) & 15);
}

__global__ __launch_bounds__(64) void swin_wave(
    const float* __restrict__ xin,    // [64][3136][128] f32
    const float* __restrict__ qkvb,   // [384]
    const float* __restrict__ projb,  // [128]
    const u16*  __restrict__ wq,      // [384][128] bf16 (Q|K|V row-major)
    const u16*  __restrict__ wp,      // [128][128] bf16
    const u16*  __restrict__ btab,    // [4][4][64][64] bf16, [n][m]
    float* __restrict__ outp)         // [64][3136][128] f32
{
  __shared__ u16 o_lds[8192];   // [64 tok][128 ci] bf16, wave-private (1 wave/block)

  const int wb = blockIdx.x;
  const int bb = wb >> 6, wy = (wb >> 3) & 7, wx = wb & 7;
  const int lane = threadIdx.x;
  const int g = lane >> 4, lj = lane & 15;
  const int cls = ((wy == 7) ? 2 : 0) | ((wx == 7) ? 1 : 0);

  auto gposf = [&](int tok) -> int {
    int t  = (tok < NTOK) ? tok : 0;
    int ti = div7(t), tj = t - ti * 7;
    int gh = wy * 7 + ti + 3; if (gh >= IMG) gh -= IMG;
    int gw = wx * 7 + tj + 3; if (gw >= IMG) gw -= IMG;
    return gh * IMG + gw;
  };

  // ---- X: whole window in regs, bf16. X[mt][ks] = rows 16mt+lj, c=32ks+8g..+7
  // (this per-lane layout serves BOTH A-frag(X) and B-frag(X^T) for K=32 MFMAs)
  const float* xb = xin + (size_t)bb * (IMG * IMG * CDIM);
  s16x8 X[4][4];
  #pragma unroll
  for (int mt = 0; mt < 4; ++mt) {
    int tok = 16 * mt + lj;
    bool ok = tok < NTOK;
    const float* xr = xb + (size_t)gposf(tok) * CDIM;
    #pragma unroll
    for (int ks = 0; ks < 4; ++ks) {
      s16x8 r = {0, 0, 0, 0, 0, 0, 0, 0};
      if (ok) {
        float4 a = *reinterpret_cast<const float4*>(xr + 32 * ks + 8 * g);
        float4 b = *reinterpret_cast<const float4*>(xr + 32 * ks + 8 * g + 4);
        r[0] = (short)f2bf(a.x); r[1] = (short)f2bf(a.y);
        r[2] = (short)f2bf(a.z); r[3] = (short)f2bf(a.w);
        r[4] = (short)f2bf(b.x); r[5] = (short)f2bf(b.y);
        r[6] = (short)f2bf(b.z); r[7] = (short)f2bf(b.w);
      }
      X[mt][ks] = r;
    }
  }

  #pragma unroll 1
  for (int h = 0; h < NHEAD; ++h) {
    // ---- K^T = Wk . X^T  (C(K^T) tile (dt,mt) == A-frag(K)[m-tile mt][kstep dt])
    s16x4 Kbf[4][2];
    #pragma unroll
    for (int dt = 0; dt < 2; ++dt) {
      s16x8 wa[4];
      #pragma unroll
      for (int ks = 0; ks < 4; ++ks)
        wa[ks] = *reinterpret_cast<const s16x8*>(
            &wq[(size_t)(128 + 32 * h + 16 * dt + lj) * 128 + 32 * ks + 8 * g]);
      f32x4 bk4 = *reinterpret_cast<const f32x4*>(&qkvb[128 + 32 * h + 16 * dt + 4 * g]);
      #pragma unroll
      for (int mt = 0; mt < 4; ++mt) {
        f32x4 c = {0.f, 0.f, 0.f, 0.f};
        #pragma unroll
        for (int ks = 0; ks < 4; ++ks) c = mfma32(wa[ks], X[mt][ks], c);
        Kbf[mt][dt] = pack4(c + bk4);
      }
    }
    // ---- Q^T = Wq . X^T  (C(Q^T) tile (dt,nt) == B-frag(Q^T)[kstep dt][n-tile nt])
    s16x4 Qbf[2][4];
    #pragma unroll
    for (int dt = 0; dt < 2; ++dt) {
      s16x8 wa[4];
      #pragma unroll
      for (int ks = 0; ks < 4; ++ks)
        wa[ks] = *reinterpret_cast<const s16x8*>(
            &wq[(size_t)(32 * h + 16 * dt + lj) * 128 + 32 * ks + 8 * g]);
      f32x4 bq4 = *reinterpret_cast<const f32x4*>(&qkvb[32 * h + 16 * dt + 4 * g]);
      #pragma unroll
      for (int nt = 0; nt < 4; ++nt) {
        f32x4 c = {0.f, 0.f, 0.f, 0.f};
        #pragma unroll
        for (int ks = 0; ks < 4; ++ks) c = mfma32(wa[ks], X[nt][ks], c);
        f32x4 q;
        #pragma unroll
        for (int r2 = 0; r2 < 4; ++r2) q[r2] = (c[r2] + bq4[r2]) * QSCALE;
        Qbf[dt][nt] = pack4(q);
      }
    }
    // ---- V = X . Wv^T  (C(V) tile (mt,dt) == A-frag(V^T)[dt][kstep mt])
    s16x4 Vbf[4][2];
    #pragma unroll
    for (int dt = 0; dt < 2; ++dt) {
      s16x8 wbv[4];
      #pragma unroll
      for (int ks = 0; ks < 4; ++ks)
        wbv[ks] = *reinterpret_cast<const s16x8*>(
            &wq[(size_t)(256 + 32 * h + 16 * dt + lj) * 128 + 32 * ks + 8 * g]);
      float bv = qkvb[256 + 32 * h + 16 * dt + lj];
      #pragma unroll
      for (int mt = 0; mt < 4; ++mt) {
        f32x4 c = {0.f, 0.f, 0.f, 0.f};
        #pragma unroll
        for (int ks = 0; ks < 4; ++ks) c = mfma32(X[mt][ks], wbv[ks], c);
        f32x4 v;
        #pragma unroll
        for (int r2 = 0; r2 < 4; ++r2) v[r2] = c[r2] + bv;
        Vbf[mt][dt] = pack4(v);
      }
    }
    // ---- S^T = K . Q^T, softmax over m (rows of S^T), per n-column-tile ----
    const u16* bt = btab + (((cls << 2) + h) << 12);
    s16x4 Pt[4][4];   // [mt][nt] B-frags of P^T
    #pragma unroll
    for (int nt = 0; nt < 4; ++nt) {
      f32x4 st[4];
      #pragma unroll
      for (int mt = 0; mt < 4; ++mt) {
        f32x4 c = mfma16(Kbf[mt][0], Qbf[0][nt], (f32x4){0.f, 0.f, 0.f, 0.f});
        c = mfma16(Kbf[mt][1], Qbf[1][nt], c);
        // bias/mask: lane holds S^T[m=16mt+4g+r2][n=16nt+lj]; btab[n][m], m consec.
        s16x4 bb4 = *reinterpret_cast<const s16x4*>(&bt[((16 * nt + lj) << 6) + 16 * mt + 4 * g]);
        #pragma unroll
        for (int r2 = 0; r2 < 4; ++r2) c[r2] += bf2f((u16)bb4[r2]);
        st[mt] = c;
      }
      float mx = -3e38f;
      #pragma unroll
      for (int mt = 0; mt < 4; ++mt)
        #pragma unroll
        for (int r2 = 0; r2 < 4; ++r2) mx = fmaxf(mx, st[mt][r2]);
      mx = fmaxf(mx, __shfl_xor(mx, 16, 64));
      mx = fmaxf(mx, __shfl_xor(mx, 32, 64));
      float sm = 0.f;
      #pragma unroll
      for (int mt = 0; mt < 4; ++mt)
        #pragma unroll
        for (int r2 = 0; r2 < 4; ++r2) {
          float e = __expf(st[mt][r2] - mx);
          st[mt][r2] = e;
          sm += e;
        }
      sm += __shfl_xor(sm, 16, 64);
      sm += __shfl_xor(sm, 32, 64);
      float inv = 1.f / sm;
      #pragma unroll
      for (int mt = 0; mt < 4; ++mt) {
        f32x4 p;
        #pragma unroll
        for (int r2 = 0; r2 < 4; ++r2) p[r2] = st[mt][r2] * inv;
        Pt[mt][nt] = pack4(p);
      }
    }
    // ---- out^T = V^T . P^T -> o_lds[n][ci] (wave-private, b64 writes) ----
    #pragma unroll
    for (int dt = 0; dt < 2; ++dt)
      #pragma unroll
      for (int nt = 0; nt < 4; ++nt) {
        f32x4 oc = {0.f, 0.f, 0.f, 0.f};
        #pragma unroll
        for (int mt = 0; mt < 4; ++mt) oc = mfma16(Vbf[mt][dt], Pt[mt][nt], oc);
        s16x4 ov = pack4(oc);
        *reinterpret_cast<s16x4*>(&o_lds[adr128(16 * nt + lj, 32 * h + 16 * dt + 4 * g)]) = ov;
      }
  }

  // ---- proj: y = o . Wp^T (A-frag(o) from o_lds; same-wave data, no barrier) ----
  float* ob = outp + (size_t)bb * (IMG * IMG * CDIM);
  #pragma unroll 1
  for (int nt = 0; nt < 4; ++nt) {
    s16x4 oa[8];
    #pragma unroll
    for (int kp = 0; kp < 8; ++kp)
      oa[kp] = *reinterpret_cast<const s16x4*>(&o_lds[adr128(16 * nt + lj, 16 * kp + 4 * g)]);
    int gp[4];
    #pragma unroll
    for (int r2 = 0; r2 < 4; ++r2) gp[r2] = gposf(16 * nt + 4 * g + r2);
    #pragma unroll
    for (int ct = 0; ct < 8; ++ct) {
      f32x4 y = {0.f, 0.f, 0.f, 0.f};
      #pragma unroll
      for (int kp = 0; kp < 8; ++kp) {
        s16x4 wpb = *reinterpret_cast<const s16x4*>(
            &wp[(size_t)(16 * ct + lj) * 128 + 16 * kp + 4 * g]);
        y = mfma16(oa[kp], wpb, y);
      }
      float bias = projb[16 * ct + lj];
      #pragma unroll
      for (int r2 = 0; r2 < 4; ++r2) {
        int tok = 16 * nt + 4 * g + r2;
        if (tok < NTOK)
          ob[(size_t)gp[r2] * CDIM + 16 * ct + lj] = y[r2] + bias;
      }
    }
  }
}

}  // namespace

extern "C" void kernel_launch(void* const* d_in, const int* in_sizes, int n_in,
                              void* d_out, int out_size, void* d_ws, size_t ws_size,
                              hipStream_t stream) {
  const float* x     = (const float*)d_in[0];
  const float* rpb   = (const float*)d_in[1];
  const float* qkvw  = (const float*)d_in[2];
  const float* qkvb  = (const float*)d_in[3];
  const float* projw = (const float*)d_in[4];
  const float* projb = (const float*)d_in[5];
  u16* wq   = (u16*)d_ws;                 // 384*128
  u16* wp   = wq + 384 * 128;             // 128*128
  u16* btab = wp + 128 * 128;             // 4*4*64*64

  prep<<<256, 256, 0, stream>>>(qkvw, projw, rpb, wq, wp, btab);
  swin_wave<<<NWIN, 64, 0, stream>>>(x, qkvb, projb, wq, wp, btab, (float*)d_out);
}